// Round 2
// baseline (2602.017 us; speedup 1.0000x reference)
//
#include <hip/hip_runtime.h>

#define B_SZ   256
#define T_SZ   1000
#define N_IN   128
#define UNITS  512

// ---------------------------------------------------------------------------
// Phase 1: C[M,512] = X[M,128] @ W[128,512],  M = B*T = 256000, fp32.
// (unchanged — measured at ~fp32 vector roofline)
// ---------------------------------------------------------------------------
__global__ __launch_bounds__(256) void gemm_in(const float* __restrict__ X,
                                               const float* __restrict__ W,
                                               float* __restrict__ C) {
    __shared__ __align__(16) float As[32][128];  // As[k][m] (transposed x tile)
    __shared__ __align__(16) float Bs[32][128];  // Bs[k][n]

    const int tid = threadIdx.x;
    const int ntile = blockIdx.x & 3;        // 512/128 = 4 n-tiles
    const int mtile = blockIdx.x >> 2;       // 2000 m-tiles
    const int m0 = mtile * 128, n0 = ntile * 128;
    const int tm  = (tid >> 4) * 8;          // 16 m-groups of 8
    const int tn4 = (tid & 15) * 4;          // 16 n-groups of 4 (+ mirror at +64)

    float acc[8][8];
#pragma unroll
    for (int i = 0; i < 8; ++i)
#pragma unroll
        for (int j = 0; j < 8; ++j) acc[i][j] = 0.0f;

    for (int k0 = 0; k0 < 128; k0 += 32) {
        __syncthreads();
#pragma unroll
        for (int r = 0; r < 4; ++r) {
            int li  = r * 256 + tid;          // 0..1023 float4 slots
            int row = li >> 3;                // 0..127
            int ch  = li & 7;                 // 0..7 (4 floats each)
            float4 a = *(const float4*)&X[(size_t)(m0 + row) * 128 + k0 + ch * 4];
            As[ch * 4 + 0][row] = a.x;
            As[ch * 4 + 1][row] = a.y;
            As[ch * 4 + 2][row] = a.z;
            As[ch * 4 + 3][row] = a.w;
        }
#pragma unroll
        for (int r = 0; r < 4; ++r) {
            int li = r * 256 + tid;
            int kk = li >> 5;                 // 0..31
            int n4 = li & 31;                 // 0..31
            *(float4*)&Bs[kk][n4 * 4] =
                *(const float4*)&W[(size_t)(k0 + kk) * 512 + n0 + n4 * 4];
        }
        __syncthreads();

#pragma unroll 8
        for (int k = 0; k < 32; ++k) {
            float4 a0 = *(const float4*)&As[k][tm];
            float4 a1 = *(const float4*)&As[k][tm + 4];
            float4 b0 = *(const float4*)&Bs[k][tn4];
            float4 b1 = *(const float4*)&Bs[k][tn4 + 64];
            const float av[8] = {a0.x, a0.y, a0.z, a0.w, a1.x, a1.y, a1.z, a1.w};
            const float bv[8] = {b0.x, b0.y, b0.z, b0.w, b1.x, b1.y, b1.z, b1.w};
#pragma unroll
            for (int i = 0; i < 8; ++i)
#pragma unroll
                for (int j = 0; j < 8; ++j)
                    acc[i][j] = fmaf(av[i], bv[j], acc[i][j]);
        }
    }

#pragma unroll
    for (int i = 0; i < 8; ++i) {
        size_t row = (size_t)(m0 + tm + i) * 512;
        float4 c0 = make_float4(acc[i][0], acc[i][1], acc[i][2], acc[i][3]);
        float4 c1 = make_float4(acc[i][4], acc[i][5], acc[i][6], acc[i][7]);
        *(float4*)&C[row + n0 + tn4]      = c0;
        *(float4*)&C[row + n0 + 64 + tn4] = c1;
    }
}

// ---------------------------------------------------------------------------
// Phase 2: ALIF scan, software-pipelined sparse i_rec.
// One WG per batch row (256 WGs x 512 threads), thread u owns unit u.
// Per step, the active-j list (ascending) is consumed in groups of 8 with:
//   - list indices prefetched 3 groups ahead (LDS latency ~120 cyc)
//   - W_rec row gathers prefetched 2 groups ahead (L2 latency ~200 cyc)
// so the steady-state iteration pays only its VALU body. The accumulator
// remains a single __fadd_rn chain in strictly ascending j (bit-identical
// to the passing r1 kernel; padded entries are predicated to exact +0.0f).
// i_in for step t+1 is prefetched at the start of step t.
// ---------------------------------------------------------------------------
__global__ __launch_bounds__(512) void alif_scan(const float* __restrict__ Wr,
                                                 float* __restrict__ IO) {
    const int b = blockIdx.x;
    const int u = threadIdx.x;
    const int w = u >> 6;                    // wave id (0..7)
    const int lane = u & 63;

    __shared__ __align__(16) int s_list[544];  // 512 + 32 pad (idx 0)
    __shared__ int s_cnt[8];
    __shared__ int s_total;

    const float DECAY   = 0.95122942450071400910f;   // exp(-1/20)
    const float OMD     = 1.0f - DECAY;
    const float DECAY_B = 0.99501247919268232342f;   // exp(-1/200)
    const float OMDB    = 1.0f - DECAY_B;

    float v = 0.0f, ad = 0.0f, z = 0.0f;

    const float* wcol = Wr + u;                       // column u of W_rec
    float* io = IO + (size_t)b * (T_SZ * UNITS) + u;  // [t][u] slab for batch b

    if (u == 0) s_total = 0;
    __syncthreads();

    float i_cur = io[0];

#define GATHER8(G, Ja, Jb)                       \
    G[0] = wcol[Ja.x * UNITS];                   \
    G[1] = wcol[Ja.y * UNITS];                   \
    G[2] = wcol[Ja.z * UNITS];                   \
    G[3] = wcol[Ja.w * UNITS];                   \
    G[4] = wcol[Jb.x * UNITS];                   \
    G[5] = wcol[Jb.y * UNITS];                   \
    G[6] = wcol[Jb.z * UNITS];                   \
    G[7] = wcol[Jb.w * UNITS];

    for (int t = 0; t < T_SZ; ++t) {
        // prefetch next step's input current (hides HBM/L2 latency fully)
        float i_next = io[(t + 1 < T_SZ ? t + 1 : t) * UNITS];

        const int cnt = s_total;
        const int niter = (cnt + 7) >> 3;

        float acc = 0.0f;
        if (niter > 0) {
            // ---- pipeline prologue ----
            int4 A0 = *(const int4*)(s_list + 0),  B0 = *(const int4*)(s_list + 4);
            int4 A1 = *(const int4*)(s_list + 8),  B1 = *(const int4*)(s_list + 12);
            int4 A2 = *(const int4*)(s_list + 16), B2 = *(const int4*)(s_list + 20);
            float G0[8], G1[8];
            GATHER8(G0, A0, B0);
            GATHER8(G1, A1, B1);
            // ---- steady loop: consume k, gathers in flight for k+1,k+2 ----
            for (int k = 0; k < niter; ++k) {
                float G2[8];
                GATHER8(G2, A2, B2);                       // issue (ready at k+2)
                int4 A3 = *(const int4*)(s_list + 8 * k + 24);
                int4 B3 = *(const int4*)(s_list + 8 * k + 28);
                const int base = k * 8;
                acc = __fadd_rn(acc, (base + 0 < cnt && A0.x != u) ? G0[0] : 0.0f);
                acc = __fadd_rn(acc, (base + 1 < cnt && A0.y != u) ? G0[1] : 0.0f);
                acc = __fadd_rn(acc, (base + 2 < cnt && A0.z != u) ? G0[2] : 0.0f);
                acc = __fadd_rn(acc, (base + 3 < cnt && A0.w != u) ? G0[3] : 0.0f);
                acc = __fadd_rn(acc, (base + 4 < cnt && B0.x != u) ? G0[4] : 0.0f);
                acc = __fadd_rn(acc, (base + 5 < cnt && B0.y != u) ? G0[5] : 0.0f);
                acc = __fadd_rn(acc, (base + 6 < cnt && B0.z != u) ? G0[6] : 0.0f);
                acc = __fadd_rn(acc, (base + 7 < cnt && B0.w != u) ? G0[7] : 0.0f);
                A0 = A1; B0 = B1; A1 = A2; B1 = B2; A2 = A3; B2 = B3;
#pragma unroll
                for (int i = 0; i < 8; ++i) { G0[i] = G1[i]; G1[i] = G2[i]; }
            }
        }

        // elementwise state update — exact reference op order, no contraction
        float newb = __fadd_rn(__fmul_rn(DECAY_B, ad), __fmul_rn(OMDB, z));
        float thr  = __fadd_rn(0.01f, __fmul_rn(newb, 1.6f));
        float it   = __fadd_rn(__fadd_rn(i_cur, acc), 0.0f);       // + ADD_CUR
        float ires = __fmul_rn(__fmul_rn(z, thr), 1.0f);           // * DT
        float newv = __fsub_rn(
            __fadd_rn(__fmul_rn(DECAY, v), __fmul_rn(OMD, it)), ires);
        float zn = (newv > thr) ? 1.0f : 0.0f;      // refractory is a no-op

        io[t * UNITS] = zn;                          // overwrite i_in with z
        v = newv; ad = newb; z = zn; i_cur = i_next;

        // rebuild active list for next step (deterministic ascending order)
        unsigned long long m = __ballot(zn > 0.0f);
        if (lane == 0) s_cnt[w] = __popcll(m);
        __syncthreads();   // [A] all waves done reading old list; cnts visible

        int base = 0, total = 0;
#pragma unroll
        for (int i = 0; i < 8; ++i) {
            int c = s_cnt[i];
            total += c;
            if (i < w) base += c;
        }
        if (zn > 0.0f) {
            int pos = base + __popcll(m & ((1ull << lane) - 1ull));
            s_list[pos] = u;
        }
        if (u == 0) s_total = total;
        if (u < 32) s_list[total + u] = 0;           // pad for pipelined reads
        __syncthreads();   // [C] list ready
    }
#undef GATHER8
}

extern "C" void kernel_launch(void* const* d_in, const int* in_sizes, int n_in,
                              void* d_out, int out_size, void* d_ws, size_t ws_size,
                              hipStream_t stream) {
    (void)in_sizes; (void)n_in; (void)out_size; (void)d_ws; (void)ws_size;
    const float* x     = (const float*)d_in[0];   // [B,T,128]
    const float* W_in  = (const float*)d_in[1];   // [128,512]
    const float* W_rec = (const float*)d_in[2];   // [512,512]
    float* out = (float*)d_out;                   // [B,T,512]

    gemm_in<<<dim3((B_SZ * T_SZ / 128) * (UNITS / 128)), dim3(256), 0, stream>>>(
        x, W_in, out);
    alif_scan<<<dim3(B_SZ), dim3(512), 0, stream>>>(W_rec, out);
}